// Round 11
// baseline (397.938 us; speedup 1.0000x reference)
//
#include <hip/hip_runtime.h>
#include <hip/hip_fp16.h>

#define CIN   64
#define COUT  128
#define HIN   128
#define WIN   128
#define HOUT  126
#define WOUT  126
#define HP    63
#define WP    63
#define NB    32
#define NG    16
#define EPS   1e-5f
#define KTOT  576            // 9 * 64, k = (kh*3+kw)*64 + ci

// LDS x-tile (f16), per buffer: [4 rows][66 cols][cell = 32 ci f16 (64B) + 16B pad = 80B]
#define CELLB 80
#define NCOLT 66
#define ROWB  (NCOLT * CELLB)   // 5280
#define XHALF (4 * ROWB)        // 21120 per buffer
#define NTILE 126               // rp*2 + ct

// tiled y: [b][co][chunk(126)][row(2)][col(64)] ; chunk = 128 floats (512B)
#define YCHUNK 128
#define YPLANE (126 * YCHUNK)   // 16128 floats per (b,co)

typedef __attribute__((ext_vector_type(8)))  _Float16 half8;
typedef __attribute__((ext_vector_type(4)))  float f32x4;
typedef __attribute__((ext_vector_type(16))) float f32x16;

// ---- weight prep: cw[co][ci][3][3] f32 -> wt[co][k] f16 hi/lo, k=(kh*3+kw)*64+ci
__global__ __launch_bounds__(256) void wprep_kernel(
    const float* __restrict__ cw, ushort* __restrict__ wh, ushort* __restrict__ wl)
{
    int idx = blockIdx.x * 256 + threadIdx.x;
    if (idx >= COUT * KTOT) return;
    int co = idx / KTOT, k = idx - co * KTOT;
    int khw = k >> 6, ci = k & 63;
    float v = cw[(co * CIN + ci) * 9 + khw];
    __half h = __float2half(v);
    __half l = __float2half(v - __half2float(h));
    wh[idx] = __half_as_ushort(h);
    wl[idx] = __half_as_ushort(l);
}

// ---- conv implicit GEMM, 32x32x16 MFMA: block = 2 rows x 64 cols x 128 couts,
// 8 waves; wave = 32 couts x (2 rows x 32 cols). ci split in 2 chunks with LDS
// double-buffer; chunk-1 global loads issued before chunk-0 compute.
__global__ __launch_bounds__(512, 4) void conv_mfma_kernel(
    const float* __restrict__ x, const ushort* __restrict__ wt_hi,
    const ushort* __restrict__ wt_lo, const float* __restrict__ cb,
    float* __restrict__ y, float* __restrict__ partials)
{
    __shared__ char xs[2 * XHALF];
    __shared__ float wred[8][4][2];

    const int tid = threadIdx.x;
    // XCD swizzle: 4032 blocks = 8 XCDs x 504; each XCD gets 4 whole images
    const int bid = blockIdx.x;
    const int w   = (bid & 7) * 504 + (bid >> 3);
    const int b   = w / 126;
    const int r   = w - b * 126;
    const int rp  = r >> 1;            // 0..62 row pair
    const int ct  = r & 1;             // col tile
    const int r0x = rp * 2;            // first x row needed (<=124; rows always valid)

    const int l = tid & 63, wid = tid >> 6;
    const int wg = wid >> 1;           // cout group of 32 (0..3)
    const int h  = wid & 1;            // col half (32 cols)
    const int l31 = l & 31, lh = l >> 5;

    f32x16 acc0 = (f32x16){0.f,0.f,0.f,0.f,0.f,0.f,0.f,0.f,
                           0.f,0.f,0.f,0.f,0.f,0.f,0.f,0.f};
    f32x16 acc1 = acc0;

    const float* xb = x + (size_t)b * (CIN * HIN * WIN);

    // main staging task (exactly 512): c4 = col quad (0..15), rr = row, cig = 4-ci group
    const int c4 = tid & 15, rr = (tid >> 4) & 3, cig = tid >> 6;
    const float* xmain = xb + (size_t)(cig * 4) * (HIN * WIN)
                       + (r0x + rr) * WIN + ct * 64 + c4 * 4;   // always in-bounds
    char* wmain = xs + rr * ROWB + (c4 * 4) * CELLB + cig * 8;

#define LOADMAIN(cip, f)                                                   \
    {                                                                      \
        _Pragma("unroll")                                                  \
        for (int q = 0; q < 4; ++q)                                        \
            f[q] = *(const f32x4*)(xmain + (size_t)((cip) * 32 + q) * (HIN * WIN)); \
    }

#define WRITEMAIN(f, buf)                                                  \
    {                                                                      \
        _Pragma("unroll")                                                  \
        for (int j = 0; j < 4; ++j) {                                      \
            ushort h0 = __half_as_ushort(__float2half(f[0][j]));           \
            ushort h1 = __half_as_ushort(__float2half(f[1][j]));           \
            ushort h2 = __half_as_ushort(__float2half(f[2][j]));           \
            ushort h3 = __half_as_ushort(__float2half(f[3][j]));           \
            uint2 hp;                                                      \
            hp.x = (unsigned)h0 | ((unsigned)h1 << 16);                    \
            hp.y = (unsigned)h2 | ((unsigned)h3 << 16);                    \
            *(uint2*)(wmain + (buf) * XHALF + j * CELLB) = hp;             \
        }                                                                  \
    }

    // tail: halo cols 64,65 (global cols ct*64+64/65; OOB for ct=1 -> zeros)
#define TAIL(cip, buf)                                                     \
    if (tid < 32) {                                                        \
        int trr = tid & 3, tcig = tid >> 2;                                \
        float2 g[4];                                                       \
        _Pragma("unroll")                                                  \
        for (int q = 0; q < 4; ++q) {                                      \
            if (ct == 0)                                                   \
                g[q] = *(const float2*)(xb                                 \
                      + (size_t)((cip) * 32 + tcig * 4 + q) * (HIN * WIN)  \
                      + (r0x + trr) * WIN + 64);                           \
            else g[q] = make_float2(0.f, 0.f);                             \
        }                                                                  \
        _Pragma("unroll")                                                  \
        for (int j = 0; j < 2; ++j) {                                      \
            float v0 = j ? g[0].y : g[0].x, v1 = j ? g[1].y : g[1].x;      \
            float v2 = j ? g[2].y : g[2].x, v3 = j ? g[3].y : g[3].x;      \
            uint2 hp;                                                      \
            hp.x = (unsigned)__half_as_ushort(__float2half(v0))            \
                 | ((unsigned)__half_as_ushort(__float2half(v1)) << 16);   \
            hp.y = (unsigned)__half_as_ushort(__float2half(v2))            \
                 | ((unsigned)__half_as_ushort(__float2half(v3)) << 16);   \
            *(uint2*)(xs + (buf) * XHALF + trr * ROWB + (64 + j) * CELLB   \
                      + tcig * 8) = hp;                                    \
        }                                                                  \
    }

    // A-fragment base: co = wg*32 + l31, k-subgroup lh (k = kstep*16 + lh*8 + j)
    const ushort* wbh = wt_hi + (size_t)(wg * 32 + l31) * KTOT + lh * 8;
    const ushort* wbl = wt_lo + (size_t)(wg * 32 + l31) * KTOT + lh * 8;
    // B-fragment base: col = h*32 + l31 (+kw), ci byte = k16*32 + lh*16
    const char* pb = xs + (h * 32 + l31) * CELLB + lh * 16;

#define COMPUTE(buf, cip)                                                  \
    {                                                                      \
        _Pragma("unroll")                                                  \
        for (int khw = 0; khw < 9; ++khw) {                                \
            const int kh = khw / 3, kw = khw - kh * 3;                     \
            _Pragma("unroll")                                              \
            for (int k16 = 0; k16 < 2; ++k16) {                            \
                half8 wh_ = *(const half8*)(wbh + khw * 64 + (cip) * 32 + k16 * 16); \
                half8 wl_ = *(const half8*)(wbl + khw * 64 + (cip) * 32 + k16 * 16); \
                half8 bv0 = *(const half8*)(pb + (buf) * XHALF             \
                            + kh * ROWB + kw * CELLB + k16 * 32);          \
                half8 bv1 = *(const half8*)(pb + (buf) * XHALF             \
                            + (1 + kh) * ROWB + kw * CELLB + k16 * 32);    \
                acc0 = __builtin_amdgcn_mfma_f32_32x32x16_f16(wh_, bv0, acc0, 0, 0, 0); \
                acc1 = __builtin_amdgcn_mfma_f32_32x32x16_f16(wh_, bv1, acc1, 0, 0, 0); \
                acc0 = __builtin_amdgcn_mfma_f32_32x32x16_f16(wl_, bv0, acc0, 0, 0, 0); \
                acc1 = __builtin_amdgcn_mfma_f32_32x32x16_f16(wl_, bv1, acc1, 0, 0, 0); \
            }                                                              \
        }                                                                  \
    }

    // ---- prologue: stage chunk 0 into buffer 0
    {
        f32x4 f0[4];
        LOADMAIN(0, f0);
        WRITEMAIN(f0, 0);
        TAIL(0, 0);
    }
    __syncthreads();

    // ---- pipelined: issue chunk-1 loads, compute chunk 0, write chunk 1
    {
        f32x4 f1[4];
        LOADMAIN(1, f1);
        __builtin_amdgcn_sched_barrier(0);   // pin loads above the compute
        COMPUTE(0, 0);
        WRITEMAIN(f1, 1);                    // vmcnt wait inserted by compiler
        TAIL(1, 1);
    }
    __syncthreads();
    COMPUTE(1, 1);

#undef LOADMAIN
#undef WRITEMAIN
#undef TAIL
#undef COMPUTE

    // ---- epilogue: bias, store y, group partials
    // C/D layout (m74/m101): spatial col = l31, cout row = (j&3)+8*(j>>2)+4*lh
    float* ybase = y + (size_t)b * COUT * YPLANE + (size_t)((rp * 2 + ct) * YCHUNK);
    const bool okcol = (ct * 64 + h * 32 + l31) < WOUT;

    float s1g[4] = {0.f, 0.f, 0.f, 0.f};
    float s2g[4] = {0.f, 0.f, 0.f, 0.f};
#pragma unroll
    for (int j = 0; j < 16; ++j) {
        int co = wg * 32 + (j & 3) + 4 * lh + 8 * (j >> 2);
        float bias = cb[co];
        float* yp = ybase + (size_t)co * YPLANE + h * 32 + l31;
        float v0 = acc0[j] + bias;
        float v1 = acc1[j] + bias;
        yp[0]  = v0;
        yp[64] = v1;
        if (okcol) {
            s1g[j >> 2] += v0 + v1;
            s2g[j >> 2] += v0 * v0 + v1 * v1;
        }
    }
#pragma unroll
    for (int g2 = 0; g2 < 4; ++g2) {
        float a = s1g[g2], q = s2g[g2];
#pragma unroll
        for (int d = 1; d < 64; d <<= 1) {
            a += __shfl_xor(a, d);
            q += __shfl_xor(q, d);
        }
        if (l == 0) {
            wred[wid][g2][0] = a;
            wred[wid][g2][1] = q;
        }
    }
    __syncthreads();

    if (tid < NG) {
        int g = tid;                       // couts [8g, 8g+8)
        int wg2 = g >> 2, g2 = g & 3;
        float t1 = wred[wg2 * 2][g2][0] + wred[wg2 * 2 + 1][g2][0];
        float t2 = wred[wg2 * 2][g2][1] + wred[wg2 * 2 + 1][g2][1];
        size_t pidx = (((size_t)b * NG + g) * NTILE + (rp * 2 + ct)) * 2;
        partials[pidx + 0] = t1;
        partials[pidx + 1] = t2;
    }
}

__global__ void stats_kernel(const float* __restrict__ partials,
                             float* __restrict__ stats)
{
    int t = blockIdx.x * blockDim.x + threadIdx.x;
    if (t >= NB * NG) return;
    float s1 = 0.f, s2 = 0.f;
    for (int j = 0; j < NTILE; ++j) {
        s1 += partials[((size_t)t * NTILE + j) * 2 + 0];
        s2 += partials[((size_t)t * NTILE + j) * 2 + 1];
    }
    const float N = 8.f * HOUT * WOUT;
    float mean = s1 / N;
    float var = s2 / N - mean * mean;
    stats[t * 2 + 0] = mean;
    stats[t * 2 + 1] = rsqrtf(var + EPS);
}

__global__ __launch_bounds__(256) void pool_kernel(
    const float* __restrict__ y, const float* __restrict__ stats,
    const float* __restrict__ gw, const float* __restrict__ gb,
    const float* __restrict__ sc, float* __restrict__ out)
{
    int idx = blockIdx.x * 256 + threadIdx.x;
    if (idx >= NB * COUT * HP * WP) return;
    int owp = idx % WP;
    int t = idx / WP;
    int ohp = t % HP; t /= HP;
    int c = t % COUT;
    int b = t / COUT;
    int g = c >> 3;

    float mean = stats[(b * NG + g) * 2 + 0];
    float rstd = stats[(b * NG + g) * 2 + 1];
    float ga = rstd * gw[c] * sc[c];
    float gbb = (gb[c] - mean * rstd * gw[c]) * sc[c];

    // tiled y: chunk = ohp*2 + (owp>>5); rows (0,1) of chunk; col = (2*owp)&63
    int ct = owp >> 5, col = (2 * owp) & 63;
    const float* yp = y + (size_t)(b * COUT + c) * YPLANE
                    + (ohp * 2 + ct) * YCHUNK + col;
    float2 r0 = *reinterpret_cast<const float2*>(yp);
    float2 r1 = *reinterpret_cast<const float2*>(yp + 64);
    float v0 = fmaf(r0.x, ga, gbb);
    float v1 = fmaf(r0.y, ga, gbb);
    float v2 = fmaf(r1.x, ga, gbb);
    float v3 = fmaf(r1.y, ga, gbb);
    float m = fmaxf(fmaxf(v0, v1), fmaxf(v2, v3));
    out[idx] = fminf(fmaxf(m, 0.f), 1.f);
}

extern "C" void kernel_launch(void* const* d_in, const int* in_sizes, int n_in,
                              void* d_out, int out_size, void* d_ws, size_t ws_size,
                              hipStream_t stream)
{
    const float* x  = (const float*)d_in[0];
    const float* cw = (const float*)d_in[1];
    const float* cbias = (const float*)d_in[2];
    const float* gw = (const float*)d_in[3];
    const float* gb = (const float*)d_in[4];
    const float* sc = (const float*)d_in[5];
    float* out = (float*)d_out;

    // ws: y 264,241,152 B + partials 1,032,192 + stats 4,096 + weights 294,912
    //   = 265,572,352 B = 253.3 MiB < 256 MiB
    const size_t YSZ = (size_t)NB * COUT * YPLANE;               // 66,060,288 f32
    float* y        = (float*)d_ws;
    float* partials = y + YSZ;                                   // 32*16*126*2 f32
    float* stats    = partials + (size_t)NB * NG * NTILE * 2;    // 1024 f32
    ushort* wh      = (ushort*)(stats + 1024);                   // 128*576 f16
    ushort* wl      = wh + (size_t)COUT * KTOT;

    hipLaunchKernelGGL(wprep_kernel, dim3((COUT * KTOT + 255) / 256), dim3(256),
                       0, stream, cw, wh, wl);

    hipLaunchKernelGGL(conv_mfma_kernel, dim3(4032), dim3(512), 0, stream,
                       x, wh, wl, cbias, y, partials);

    hipLaunchKernelGGL(stats_kernel, dim3(2), dim3(256), 0, stream,
                       partials, stats);

    int total = NB * COUT * HP * WP;
    hipLaunchKernelGGL(pool_kernel, dim3((total + 255) / 256), dim3(256), 0, stream,
                       y, stats, gw, gb, sc, out);
}